// Round 5
// baseline (1191.730 us; speedup 1.0000x reference)
//
#include <hip/hip_runtime.h>
#include <cstdint>
#include <cstddef>

// Problem constants (B=4, S=2048, K=4096, N=11008, G=128)
#define M_DIM 8192
#define K_DIM 4096
#define N_DIM 11008
#define NT    (K_DIM / 64)   // 64 K-tiles of BK=64

typedef short bf16x8 __attribute__((ext_vector_type(8)));
typedef float f32x4  __attribute__((ext_vector_type(4)));
typedef unsigned short us8 __attribute__((ext_vector_type(8)));

__device__ __forceinline__ unsigned short f2bf(float f) {
  unsigned int u = __float_as_uint(f);
  u += 0x7FFFu + ((u >> 16) & 1u);
  return (unsigned short)(u >> 16);
}

// ---------------- kernel 1: x fp32 -> bf16 ----------------
__global__ __launch_bounds__(256) void cvt_x_kernel(const float* __restrict__ x,
                                                    unsigned short* __restrict__ xb) {
  const int i = blockIdx.x * 256 + threadIdx.x;
  const float4* x4 = (const float4*)x;
  float4 a = x4[(size_t)i * 2];
  float4 b = x4[(size_t)i * 2 + 1];
  us8 o;
  o[0] = f2bf(a.x); o[1] = f2bf(a.y); o[2] = f2bf(a.z); o[3] = f2bf(a.w);
  o[4] = f2bf(b.x); o[5] = f2bf(b.y); o[6] = f2bf(b.z); o[7] = f2bf(b.w);
  *(us8*)(xb + (size_t)i * 8) = o;
}

// ---------------- kernel 2: dequant int4 -> bf16 W^T (N x K) ----------------
// 64x64 tile via LDS transpose, chunk-swizzled conflict-free both sides.
__global__ __launch_bounds__(256) void dequant_kernel(const int* __restrict__ qw,
                                                      const float* __restrict__ sc,
                                                      unsigned short* __restrict__ wt) {
  const int n0 = blockIdx.x * 64;
  const int k0 = blockIdx.y * 64;
  const int g  = blockIdx.y >> 1;
  __shared__ unsigned short lds[64 * 64];
  const int t = threadIdx.x;
  {
    const int kk_l = t >> 5;
    const int n_l  = (t & 31) * 2;
    const int key  = (n_l >> 1) & 7;
    const int2  q2 = *(const int2*)&qw[(k0 / 8 + kk_l) * N_DIM + n0 + n_l];
    const float2 s2 = *(const float2*)&sc[g * N_DIM + n0 + n_l];
    us8 o0, o1;
#pragma unroll
    for (int j = 0; j < 8; ++j) {
      o0[j] = f2bf((float)(((q2.x >> (4 * j)) & 15) - 8) * s2.x);
      o1[j] = f2bf((float)(((q2.y >> (4 * j)) & 15) - 8) * s2.y);
    }
    const int pch = (kk_l ^ key) * 8;
    *(us8*)&lds[(n_l    ) * 64 + pch] = o0;
    *(us8*)&lds[(n_l + 1) * 64 + pch] = o1;
  }
  __syncthreads();
#pragma unroll
  for (int it = 0; it < 2; ++it) {
    const int idx = t + it * 256;
    const int n_l = idx >> 3;
    const int ch  = idx & 7;
    const int pch = (ch ^ ((n_l >> 1) & 7)) * 8;
    *(us8*)&wt[(size_t)(n0 + n_l) * K_DIM + k0 + ch * 8] = *(const us8*)&lds[n_l * 64 + pch];
  }
}

// ---------------- kernel 3: 256x256 8-phase bf16 MFMA GEMM ----------------
__device__ __forceinline__ void gl_lds(const unsigned short* g, unsigned short* l) {
  __builtin_amdgcn_global_load_lds(
      (const __attribute__((address_space(1))) unsigned int*)g,
      (__attribute__((address_space(3))) unsigned int*)l, 16, 0, 0);
}

template<int N> __device__ __forceinline__ void vwait() {
  if constexpr (N == 8) asm volatile("s_waitcnt vmcnt(8)" ::: "memory");
  if constexpr (N == 4) asm volatile("s_waitcnt vmcnt(4)" ::: "memory");
  if constexpr (N == 0) asm volatile("s_waitcnt vmcnt(0)" ::: "memory");
}

__device__ __forceinline__ void mfma16(const bf16x8 (&a)[4], const bf16x8 (&b)[4],
                                       f32x4 (&acc)[8][4], int mo) {
#pragma unroll
  for (int mi = 0; mi < 4; ++mi)
#pragma unroll
    for (int ni = 0; ni < 4; ++ni)
      acc[mi + mo][ni] = __builtin_amdgcn_mfma_f32_16x16x32_bf16(a[mi], b[ni], acc[mi + mo][ni], 0, 0, 0);
}

// One K-tile = 4 phases. Stages: P1/P2 -> (t+1) h1 regions (S12), P3/P4 -> (t+2)
// h0 regions (S34). Waits: W2 end of P2 (retires A/B[t]h1, 5-6 phases old),
// W1 end of P4 (retires A/B[t+1]h0, 6-7 phases old). All buffer pointers are
// compile-time after inlining (unrolled 2-tile loop body).
template<int W2N, int W1N, bool S12, bool S34>
__device__ __forceinline__ void tile_step(
    const unsigned short* Ah0, const unsigned short* Ah1,
    const unsigned short* Bh0, const unsigned short* Bh1,
    unsigned short* stA1, unsigned short* stB1,
    unsigned short* stA2, unsigned short* stB2,
    const unsigned short* gA0, const unsigned short* gA1,
    const unsigned short* gB0, const unsigned short* gB1,
    int off1, int off2, int aoffA, int aoffB, int t8,
    f32x4 (&acc)[8][4]) {
  bf16x8 a[4], b[4], a2[4];

  // ---- P1: h0, m-half 0 ----
#pragma unroll
  for (int i = 0; i < 4; ++i) a[i] = *(const bf16x8*)&Ah0[aoffA + i * 512];
#pragma unroll
  for (int i = 0; i < 4; ++i) b[i] = *(const bf16x8*)&Bh0[aoffB + i * 512];
  if constexpr (S12) { gl_lds(gA0 + off1, stA1 + t8); gl_lds(gA1 + off1, stA1 + 4096 + t8); }
  __builtin_amdgcn_s_barrier();
  __builtin_amdgcn_s_setprio(1);
  mfma16(a, b, acc, 0);
  __builtin_amdgcn_s_setprio(0);
  __builtin_amdgcn_s_barrier();

  // ---- P2: h0, m-half 1 (b reused) ----
#pragma unroll
  for (int i = 0; i < 4; ++i) a2[i] = *(const bf16x8*)&Ah0[aoffA + (i + 4) * 512];
  if constexpr (S12) { gl_lds(gB0 + off1, stB1 + t8); gl_lds(gB1 + off1, stB1 + 4096 + t8); }
  __builtin_amdgcn_s_barrier();
  __builtin_amdgcn_s_setprio(1);
  mfma16(a2, b, acc, 4);
  __builtin_amdgcn_s_setprio(0);
  vwait<W2N>();
  __builtin_amdgcn_s_barrier();

  // ---- P3: h1, m-half 0 ----
#pragma unroll
  for (int i = 0; i < 4; ++i) a[i] = *(const bf16x8*)&Ah1[aoffA + i * 512];
#pragma unroll
  for (int i = 0; i < 4; ++i) b[i] = *(const bf16x8*)&Bh1[aoffB + i * 512];
  if constexpr (S34) { gl_lds(gA0 + off2, stA2 + t8); gl_lds(gA1 + off2, stA2 + 4096 + t8); }
  __builtin_amdgcn_s_barrier();
  __builtin_amdgcn_s_setprio(1);
  mfma16(a, b, acc, 0);
  __builtin_amdgcn_s_setprio(0);
  __builtin_amdgcn_s_barrier();

  // ---- P4: h1, m-half 1 ----
#pragma unroll
  for (int i = 0; i < 4; ++i) a2[i] = *(const bf16x8*)&Ah1[aoffA + (i + 4) * 512];
  if constexpr (S34) { gl_lds(gB0 + off2, stB2 + t8); gl_lds(gB1 + off2, stB2 + 4096 + t8); }
  __builtin_amdgcn_s_barrier();
  __builtin_amdgcn_s_setprio(1);
  mfma16(a2, b, acc, 4);
  __builtin_amdgcn_s_setprio(0);
  vwait<W1N>();
  __builtin_amdgcn_s_barrier();
}

__global__ __launch_bounds__(512, 2) void gemm_kernel(const unsigned short* __restrict__ A,
                                                      const unsigned short* __restrict__ Bt,
                                                      float* __restrict__ C) {
  __shared__ unsigned short lds[8][8192];   // [0..3]=A {E.h0,E.h1,O.h0,O.h1}, [4..7]=B same
  unsigned short* AE0 = &lds[0][0]; unsigned short* AE1 = &lds[1][0];
  unsigned short* AO0 = &lds[2][0]; unsigned short* AO1 = &lds[3][0];
  unsigned short* BE0 = &lds[4][0]; unsigned short* BE1 = &lds[5][0];
  unsigned short* BO0 = &lds[6][0]; unsigned short* BO1 = &lds[7][0];

  const int t    = threadIdx.x;
  const int wave = t >> 6;
  const int lane = t & 63;
  const int l15  = lane & 15;
  const int wr   = wave >> 2;    // 0..1
  const int wc   = wave & 3;     // 0..3
  const int t8   = t * 8;

  // XCD swizzle (bijective, 1376 = 8*172) + m-fastest within chunk:
  // 32 consecutive wgs on one XCD share a single 2MB B-panel (fits XCD L2).
  const int bid = blockIdx.x;
  const int wg  = (bid & 7) * 172 + (bid >> 3);
  const int m0  = (wg & 31) * 256;    // 1376 = 32*43, wg%32 -> m (fast), wg/32 -> n
  const int n0  = (wg >> 5) * 256;

  // staging: thread t covers region rows (t>>2)+128j, phys chunk (t&3); pre-swizzle src chunk
  const int sq = (t & 3) ^ ((t >> 3) & 3);
  const unsigned short* gA0 = A  + (size_t)(m0 + (t >> 2)) * K_DIM + sq * 8;
  const unsigned short* gB0 = Bt + (size_t)(n0 + (t >> 2)) * K_DIM + sq * 8;
  const unsigned short* gA1 = gA0 + (size_t)128 * K_DIM;
  const unsigned short* gB1 = gB0 + (size_t)128 * K_DIM;

  // ds_read swizzled fragment offsets
  const int sxo   = ((lane >> 4) ^ ((l15 >> 1) & 3)) << 3;
  const int aoffA = (wr * 128 + l15) * 32 + sxo;
  const int aoffB = (wc * 64  + l15) * 32 + sxo;

  f32x4 acc[8][4] = {};

  // ---- prologue: t0{h0,h1} + t1{h0} (12 issues), retire t0h0 (oldest 4) ----
  gl_lds(gA0,      AE0 + t8); gl_lds(gA1,      AE0 + 4096 + t8);
  gl_lds(gB0,      BE0 + t8); gl_lds(gB1,      BE0 + 4096 + t8);
  gl_lds(gA0 + 32, AE1 + t8); gl_lds(gA1 + 32, AE1 + 4096 + t8);
  gl_lds(gB0 + 32, BE1 + t8); gl_lds(gB1 + 32, BE1 + 4096 + t8);
  gl_lds(gA0 + 64, AO0 + t8); gl_lds(gA1 + 64, AO0 + 4096 + t8);
  gl_lds(gB0 + 64, BO0 + t8); gl_lds(gB1 + 64, BO0 + 4096 + t8);
  vwait<8>();
  __builtin_amdgcn_s_barrier();

  // ---- main loop: 2 K-tiles per iteration, compile-time buffers ----
  const unsigned short* gAr0 = gA0; const unsigned short* gAr1 = gA1;
  const unsigned short* gBr0 = gB0; const unsigned short* gBr1 = gB1;
#pragma unroll 1
  for (int e = 0; e < NT - 2; e += 2) {
    // even tile e: read {E}, stage (e+1)h1 -> {AO1,BO1}, (e+2)h0 -> {AE0,BE0}
    tile_step<8, 8, true, true>(AE0, AE1, BE0, BE1, AO1, BO1, AE0, BE0,
                                gAr0, gAr1, gBr0, gBr1, 96, 128, aoffA, aoffB, t8, acc);
    // odd tile e+1: read {O}, stage (e+2)h1 -> {AE1,BE1}, (e+3)h0 -> {AO0,BO0}
    tile_step<8, 8, true, true>(AO0, AO1, BO0, BO1, AE1, BE1, AO0, BO0,
                                gAr0, gAr1, gBr0, gBr1, 160, 192, aoffA, aoffB, t8, acc);
    gAr0 += 128; gAr1 += 128; gBr0 += 128; gBr1 += 128;
  }
  // ---- peeled last pair (tiles 62,63): stage 63h1 only; drain 8->4->0 ----
  tile_step<8, 4, true, false>(AE0, AE1, BE0, BE1, AO1, BO1, AE0, BE0,
                               gAr0, gAr1, gBr0, gBr1, 96, 128, aoffA, aoffB, t8, acc);
  tile_step<0, -1, false, false>(AO0, AO1, BO0, BO1, AE1, BE1, AO0, BO0,
                                 gAr0, gAr1, gBr0, gBr1, 160, 192, aoffA, aoffB, t8, acc);

  // ---- epilogue: C/D layout col=lane&15, row=(lane>>4)*4+reg ----
  const int cn = n0 + wc * 64 + l15;
  const int rm = m0 + wr * 128 + (lane >> 4) * 4;
#pragma unroll
  for (int mi = 0; mi < 8; ++mi)
#pragma unroll
    for (int ni = 0; ni < 4; ++ni)
#pragma unroll
      for (int r = 0; r < 4; ++r)
        C[(size_t)(rm + mi * 16 + r) * N_DIM + cn + ni * 16] = acc[mi][ni][r];
}

extern "C" void kernel_launch(void* const* d_in, const int* in_sizes, int n_in,
                              void* d_out, int out_size, void* d_ws, size_t ws_size,
                              hipStream_t stream) {
  const float* x  = (const float*)d_in[0];
  const int*   qw = (const int*)d_in[1];
  const float* sc = (const float*)d_in[2];
  float* out = (float*)d_out;

  unsigned short* xb = (unsigned short*)d_ws;                                      // 64 MB
  unsigned short* wt = (unsigned short*)((char*)d_ws + (size_t)M_DIM * K_DIM * 2); // +86 MB

  cvt_x_kernel<<<dim3(M_DIM * K_DIM / (8 * 256)), dim3(256), 0, stream>>>(x, xb);
  dequant_kernel<<<dim3(N_DIM / 64, K_DIM / 64), dim3(256), 0, stream>>>(qw, sc, wt);
  gemm_kernel<<<dim3((N_DIM / 256) * (M_DIM / 256)), dim3(512), 0, stream>>>(xb, wt, out);
}